// Round 2
// baseline (6610.409 us; speedup 1.0000x reference)
//
#include <hip/hip_runtime.h>
#include <math.h>

constexpr int Hh = 256, Ww = 256, HW = 65536;
constexpr int NX = 393216;          // B*C*H*W
constexpr int NU = 786432;          // B*C*2*H*W
constexpr int GRIDN = 384;
constexpr int BLKN  = 256;
constexpr int TN    = GRIDN * BLKN; // 98304 == NX/4 exactly
constexpr int KSTEPS = 50;

__global__ void zero_cnt(unsigned* cnt) { *cnt = 0u; }

__device__ __forceinline__ float4 ld4(const float* p, int c4) {
    return ((const float4*)p)[c4];
}
__device__ __forceinline__ void st4(float* p, int c4, float4 val) {
    ((float4*)p)[c4] = val;
}

__device__ __forceinline__ void grid_barrier(unsigned* cnt, unsigned target) {
    __threadfence();
    __syncthreads();
    if (threadIdx.x == 0) {
        __hip_atomic_fetch_add(cnt, 1u, __ATOMIC_ACQ_REL, __HIP_MEMORY_SCOPE_AGENT);
        while (__hip_atomic_load(cnt, __ATOMIC_ACQUIRE, __HIP_MEMORY_SCOPE_AGENT) < target) {
            __builtin_amdgcn_s_sleep(2);
        }
    }
    __syncthreads();
}

__global__ void __launch_bounds__(BLKN) cp_persist(
    const float* __restrict__ y, const float* __restrict__ lambd,
    float* __restrict__ x, float* __restrict__ xt, float* __restrict__ u,
    float* __restrict__ v, float* __restrict__ partials, unsigned* __restrict__ cnt)
{
    const int tid = blockIdx.x * BLKN + threadIdx.x;
    __shared__ float4 sred[BLKN];
    __shared__ float4 s_scale;

    // ---------- init: x = y, xt = 0, u = nabla(y). x-chunk = tid ----------
    {
        const int c = tid;
        const int bc = c >> 14;            // b*C + cch, in [0,6)
        const int off4 = c & 16383;
        const int off = off4 << 2;
        const int h = off >> 8;
        const int w0 = off & 255;
        float4 yv = ld4(y, c);
        st4(x, c, yv);
        st4(xt, c, make_float4(0.f, 0.f, 0.f, 0.f));
        float4 dh = make_float4(0.f, 0.f, 0.f, 0.f);
        if (h < Hh - 1) {
            float4 b2 = ld4(y, c + 64);
            dh.x = b2.x - yv.x; dh.y = b2.y - yv.y; dh.z = b2.z - yv.z; dh.w = b2.w - yv.w;
        }
        float4 dw;
        dw.x = yv.y - yv.x; dw.y = yv.z - yv.y; dw.z = yv.w - yv.z;
        dw.w = (w0 < 252) ? (y[(c << 2) + 4] - yv.w) : 0.f;
        const int i04 = (bc << 15) + off4;  // (bc*2)*16384 + off4
        st4(u, i04, dh);
        st4(u, i04 + 16384, dw);
    }

    unsigned epoch = 1;
    grid_barrier(cnt, epoch * GRIDN);

    float sigma = 0.20412414523193150818f;  // 0.5/sqrt(6)
    float tau   = sigma;
    const int d0 = (tid >> 14) & 1;              // direction of both u-chunks
    const int bx = ((tid >> 14) >= 3) ? 1 : 0;   // batch of x-chunk

    // phase A on one u-chunk: v = u + sigma*nabla(xt); returns dot(v,v)
    auto phaseA = [&](int c) -> float {
        const int bcd = c >> 14;                 // in [0,12)
        const int d = bcd & 1;
        const int off4 = c & 16383;
        const int off = off4 << 2;
        const int h = off >> 8;
        const int w0 = off & 255;
        const int jx4 = ((bcd >> 1) << 14) + off4;
        float4 g4 = make_float4(0.f, 0.f, 0.f, 0.f);
        if (d == 0) {
            if (h < Hh - 1) {
                float4 a = ld4(xt, jx4);
                float4 b2 = ld4(xt, jx4 + 64);
                g4.x = b2.x - a.x; g4.y = b2.y - a.y; g4.z = b2.z - a.z; g4.w = b2.w - a.w;
            }
        } else {
            float4 a = ld4(xt, jx4);
            g4.x = a.y - a.x; g4.y = a.z - a.y; g4.z = a.w - a.z;
            g4.w = (w0 < 252) ? (xt[(jx4 << 2) + 4] - a.w) : 0.f;
        }
        float4 uu = ld4(u, c);
        float4 vv;
        vv.x = fmaf(sigma, g4.x, uu.x);
        vv.y = fmaf(sigma, g4.y, uu.y);
        vv.z = fmaf(sigma, g4.z, uu.z);
        vv.w = fmaf(sigma, g4.w, uu.w);
        st4(v, c, vv);
        return vv.x*vv.x + vv.y*vv.y + vv.z*vv.z + vv.w*vv.w;
    };

    for (int t = 0; t < KSTEPS; ++t) {
        // ---------- phase A: chunks tid (b=0) and tid+TN (b=1) ----------
        float sa = phaseA(tid);
        float sb = phaseA(tid + TN);
        float4 accv;
        accv.x = d0 ? 0.f : sa;   // group 0 = (b0,d0)
        accv.y = d0 ? sa  : 0.f;  // group 1 = (b0,d1)
        accv.z = d0 ? 0.f : sb;   // group 2 = (b1,d0)
        accv.w = d0 ? sb  : 0.f;  // group 3 = (b1,d1)
        sred[threadIdx.x] = accv;
        __syncthreads();
        for (int s = BLKN >> 1; s > 0; s >>= 1) {
            if ((int)threadIdx.x < s) {
                float4 a = sred[threadIdx.x], b2 = sred[threadIdx.x + s];
                a.x += b2.x; a.y += b2.y; a.z += b2.z; a.w += b2.w;
                sred[threadIdx.x] = a;
            }
            __syncthreads();
        }
        if (threadIdx.x == 0) st4(partials, blockIdx.x, sred[0]);

        epoch++;
        grid_barrier(cnt, epoch * GRIDN);

        // ---------- finish reduction redundantly per block ----------
        {
            float4 p = ld4(partials, threadIdx.x);
            if ((int)threadIdx.x + BLKN < GRIDN) {
                float4 q = ld4(partials, threadIdx.x + BLKN);
                p.x += q.x; p.y += q.y; p.z += q.z; p.w += q.w;
            }
            sred[threadIdx.x] = p;
            __syncthreads();
            for (int s = BLKN >> 1; s > 0; s >>= 1) {
                if ((int)threadIdx.x < s) {
                    float4 a = sred[threadIdx.x], b2 = sred[threadIdx.x + s];
                    a.x += b2.x; a.y += b2.y; a.z += b2.z; a.w += b2.w;
                    sred[threadIdx.x] = a;
                }
                __syncthreads();
            }
            if (threadIdx.x == 0) {
                float lamb = expf(lambd[0]);
                float4 sres = sred[0];
                float4 sc;
                sc.x = lamb / fmaxf(sqrtf(sres.x), lamb);
                sc.y = lamb / fmaxf(sqrtf(sres.y), lamb);
                sc.z = lamb / fmaxf(sqrtf(sres.z), lamb);
                sc.w = lamb / fmaxf(sqrtf(sres.w), lamb);
                s_scale = sc;
            }
            __syncthreads();
        }

        const float chi = 1.0f / sqrtf(1.0f + tau);

        // ---------- phase B: u' = v*scale; x,xt update. x-chunk = tid ----------
        {
            const float s0 = bx ? s_scale.z : s_scale.x;
            const float s1 = bx ? s_scale.w : s_scale.y;
            const int c = tid;
            const int bc = c >> 14;
            const int off4 = c & 16383;
            const int off = off4 << 2;
            const int h = off >> 8;
            const int w0 = off & 255;
            const int i04 = (bc << 15) + off4;
            const int i14 = i04 + 16384;
            float4 v0 = ld4(v, i04);
            float4 v1 = ld4(v, i14);
            float4 u0, u1;
            u0.x = v0.x*s0; u0.y = v0.y*s0; u0.z = v0.z*s0; u0.w = v0.w*s0;
            u1.x = v1.x*s1; u1.y = v1.y*s1; u1.z = v1.z*s1; u1.w = v1.w*s1;
            st4(u, i04, u0);
            st4(u, i14, u1);
            float nt0 = 0.f, nt1 = 0.f, nt2 = 0.f, nt3 = 0.f;
            if (h > 0) {
                float4 v0m = ld4(v, i04 - 64);
                nt0 += v0m.x*s0; nt1 += v0m.y*s0; nt2 += v0m.z*s0; nt3 += v0m.w*s0;
            }
            if (h < Hh - 1) {
                nt0 -= u0.x; nt1 -= u0.y; nt2 -= u0.z; nt3 -= u0.w;
            }
            if (w0 > 0) nt0 += v[(i14 << 2) - 1] * s1;
            nt1 += u1.x; nt2 += u1.y; nt3 += u1.z;
            nt0 -= u1.x; nt1 -= u1.y; nt2 -= u1.z;
            if (w0 < 252) nt3 -= u1.w;
            float4 xo = ld4(x, c);
            float4 yv = ld4(y, c);
            const float inv = 1.0f / (1.0f + tau);
            float4 xn, xtn;
            xn.x = (xo.x + tau*(yv.x - nt0)) * inv;
            xn.y = (xo.y + tau*(yv.y - nt1)) * inv;
            xn.z = (xo.z + tau*(yv.z - nt2)) * inv;
            xn.w = (xo.w + tau*(yv.w - nt3)) * inv;
            const float opc = 1.f + chi;
            xtn.x = opc*xn.x - chi*xo.x;
            xtn.y = opc*xn.y - chi*xo.y;
            xtn.z = opc*xn.z - chi*xo.z;
            xtn.w = opc*xn.w - chi*xo.w;
            st4(x, c, xn);
            st4(xt, c, xtn);
        }

        epoch++;
        grid_barrier(cnt, epoch * GRIDN);

        tau   *= chi;
        sigma /= chi;
    }
}

extern "C" void kernel_launch(void* const* d_in, const int* in_sizes, int n_in,
                              void* d_out, int out_size, void* d_ws, size_t ws_size,
                              hipStream_t stream) {
    (void)in_sizes; (void)n_in; (void)out_size; (void)ws_size;
    const float* y     = (const float*)d_in[0];
    const float* lambd = (const float*)d_in[1];
    float* x  = (float*)d_out;          // [0 , NX)
    float* xt = x + NX;                 // [NX, 2NX)
    float* u  = x + 2 * NX;             // [2NX, 2NX+NU)
    float* v        = (float*)d_ws;     // NU floats
    float* partials = v + NU;           // GRIDN float4s
    unsigned* cnt   = (unsigned*)(partials + 4 * GRIDN);

    zero_cnt<<<1, 1, 0, stream>>>(cnt);
    cp_persist<<<GRIDN, BLKN, 0, stream>>>(y, lambd, x, xt, u, v, partials, cnt);
}

// Round 3
// 328.778 us; speedup vs baseline: 20.1060x; 20.1060x over previous
//
#include <hip/hip_runtime.h>
#include <math.h>

constexpr int Cc = 3, Hh = 256;
constexpr int HW = 65536;
constexpr int NX = 393216;   // 2*3*256*256
constexpr int NU = 786432;
constexpr int R = 8;         // rows per tile
constexpr int NBLK = 192;    // 6 images * 32 tiles
constexpr int KSTEPS = 50;

__device__ __forceinline__ float4 ld4(const float* p, int i) { return ((const float4*)p)[i]; }
__device__ __forceinline__ void st4(float* p, int i, float4 v) { ((float4*)p)[i] = v; }
__device__ __forceinline__ float4 mk4(float a, float b, float c, float d) { return make_float4(a, b, c, d); }

// s=0: x=y, v0 = nabla(y) (xt0=0 so v0=u0), partials, xtop halo copy
__global__ void __launch_bounds__(256) cp_kA(const float* __restrict__ y,
        float* __restrict__ x, float* __restrict__ vout,
        float* __restrict__ pout, float* __restrict__ xtop)
{
    __shared__ float4 sred[256];
    const int tid = threadIdx.x;
    const int blk = blockIdx.x;
    const int bc = blk >> 5;
    const int r0 = (blk & 31) * R;
    const int c4 = tid & 63;
    const int trow = tid >> 6;
    const int b = (bc >= Cc) ? 1 : 0;
    float pa0 = 0.f, pa1 = 0.f;
    #pragma unroll
    for (int k = 0; k < 2; ++k) {
        const int rr = trow + 4 * k;
        const int gh = r0 + rr;
        const int j4 = bc * 16384 + gh * 64 + c4;
        const float4 yv = ld4(y, j4);
        float4 dh = mk4(0, 0, 0, 0);
        if (gh < Hh - 1) {
            float4 yn = ld4(y, j4 + 64);
            dh.x = yn.x - yv.x; dh.y = yn.y - yv.y; dh.z = yn.z - yv.z; dh.w = yn.w - yv.w;
        }
        float4 dw;
        dw.x = yv.y - yv.x; dw.y = yv.z - yv.y; dw.z = yv.w - yv.z;
        dw.w = (c4 < 63) ? (y[4 * j4 + 4] - yv.w) : 0.f;
        st4(x, j4, yv);
        const int iv4 = bc * 32768 + gh * 64 + c4;
        st4(vout, iv4, dh);
        st4(vout, iv4 + 16384, dw);
        pa0 += dh.x*dh.x + dh.y*dh.y + dh.z*dh.z + dh.w*dh.w;
        pa1 += dw.x*dw.x + dw.y*dw.y + dw.z*dw.z + dw.w*dw.w;
        if (rr == 0) st4(xtop, blk * 64 + c4, yv);
    }
    sred[tid] = b ? mk4(0.f, 0.f, pa0, pa1) : mk4(pa0, pa1, 0.f, 0.f);
    __syncthreads();
    for (int s = 128; s > 0; s >>= 1) {
        if (tid < s) {
            float4 a = sred[tid], bb = sred[tid + s];
            a.x += bb.x; a.y += bb.y; a.z += bb.z; a.w += bb.w;
            sred[tid] = a;
        }
        __syncthreads();
    }
    if (tid == 0) st4(pout, blk, sred[0]);
}

// fused: scales(s-1) -> phaseB(s-1) [x update, xt' into LDS incl. halo row] -> phaseA(s) [v_next + partials]
__global__ void __launch_bounds__(256) cp_kB(const float* __restrict__ y,
        const float* __restrict__ lambd, float* __restrict__ x,
        const float* __restrict__ vprev, float* __restrict__ vnext,
        const float* __restrict__ pprev, float* __restrict__ pnext,
        const float* __restrict__ xtop_prev, float* __restrict__ xtop_next,
        float sigma, float tau, float chi)
{
    __shared__ float4 sred[256];
    __shared__ float sxt[(R + 1) * 256];
    __shared__ float4 s_scale;
    const int tid = threadIdx.x;
    const int blk = blockIdx.x;
    const int bc = blk >> 5;
    const int r0 = (blk & 31) * R;
    const int c4 = tid & 63;
    const int trow = tid >> 6;
    const int b = (bc >= Cc) ? 1 : 0;

    // ---- scales from previous step's partials (fixed-order, redundant per block) ----
    sred[tid] = (tid < NBLK) ? ld4(pprev, tid) : mk4(0, 0, 0, 0);
    __syncthreads();
    for (int s = 128; s > 0; s >>= 1) {
        if (tid < s) {
            float4 a = sred[tid], bb = sred[tid + s];
            a.x += bb.x; a.y += bb.y; a.z += bb.z; a.w += bb.w;
            sred[tid] = a;
        }
        __syncthreads();
    }
    if (tid == 0) {
        const float lamb = expf(lambd[0]);
        float4 S = sred[0];
        s_scale = mk4(lamb / fmaxf(sqrtf(S.x), lamb), lamb / fmaxf(sqrtf(S.y), lamb),
                      lamb / fmaxf(sqrtf(S.z), lamb), lamb / fmaxf(sqrtf(S.w), lamb));
    }
    __syncthreads();
    const float s0 = b ? s_scale.z : s_scale.x;
    const float s1 = b ? s_scale.w : s_scale.y;

    // ---- phase B (step s-1): rows rr=0..R (row R redundant halo) ----
    const float inv = 1.0f / (1.0f + tau);
    const float opc = 1.0f + chi;
    float4 u0k[2], u1k[2];
    #pragma unroll
    for (int k = 0; k < 3; ++k) {
        const int rr = trow + 4 * k;
        if (rr <= R) {
            const int gh = r0 + rr;
            if (gh < Hh) {
                const bool halo = (rr == R);
                const int j4 = bc * 16384 + gh * 64 + c4;
                const int iv4 = bc * 32768 + gh * 64 + c4;
                const float4 v0 = ld4(vprev, iv4);
                const float4 v1 = ld4(vprev, iv4 + 16384);
                float4 u0, u1;
                u0.x = v0.x*s0; u0.y = v0.y*s0; u0.z = v0.z*s0; u0.w = v0.w*s0;
                u1.x = v1.x*s1; u1.y = v1.y*s1; u1.z = v1.z*s1; u1.w = v1.w*s1;
                float nt0 = 0.f, nt1 = 0.f, nt2 = 0.f, nt3 = 0.f;
                if (gh > 0) {
                    float4 vm = ld4(vprev, iv4 - 64);
                    nt0 += vm.x*s0; nt1 += vm.y*s0; nt2 += vm.z*s0; nt3 += vm.w*s0;
                }
                if (gh < Hh - 1) { nt0 -= u0.x; nt1 -= u0.y; nt2 -= u0.z; nt3 -= u0.w; }
                if (c4 > 0) nt0 += vprev[((iv4 + 16384) << 2) - 1] * s1;
                nt1 += u1.x; nt2 += u1.y; nt3 += u1.z;
                nt0 -= u1.x; nt1 -= u1.y; nt2 -= u1.z;
                if (c4 < 63) nt3 -= u1.w;
                const float4 xo = halo ? ld4(xtop_prev, (blk + 1) * 64 + c4) : ld4(x, j4);
                const float4 yv = ld4(y, j4);
                float4 xp, xtp;
                xp.x = (xo.x + tau * (yv.x - nt0)) * inv;
                xp.y = (xo.y + tau * (yv.y - nt1)) * inv;
                xp.z = (xo.z + tau * (yv.z - nt2)) * inv;
                xp.w = (xo.w + tau * (yv.w - nt3)) * inv;
                xtp.x = opc * xp.x - chi * xo.x;
                xtp.y = opc * xp.y - chi * xo.y;
                xtp.z = opc * xp.z - chi * xo.z;
                xtp.w = opc * xp.w - chi * xo.w;
                ((float4*)(sxt + rr * 256))[c4] = xtp;
                if (!halo) {
                    st4(x, j4, xp);
                    if (k < 2) { u0k[k] = u0; u1k[k] = u1; }
                    if (rr == 0) st4(xtop_next, blk * 64 + c4, xp);
                }
            }
        }
    }
    __syncthreads();

    // ---- phase A (step s): v_next = u' + sigma * nabla(xt'), partials ----
    float pa0 = 0.f, pa1 = 0.f;
    #pragma unroll
    for (int k = 0; k < 2; ++k) {
        const int rr = trow + 4 * k;
        const int gh = r0 + rr;
        const float4 xt0 = ((const float4*)(sxt + rr * 256))[c4];
        float4 dh = mk4(0, 0, 0, 0);
        if (gh < Hh - 1) {
            float4 xn = ((const float4*)(sxt + (rr + 1) * 256))[c4];
            dh.x = xn.x - xt0.x; dh.y = xn.y - xt0.y; dh.z = xn.z - xt0.z; dh.w = xn.w - xt0.w;
        }
        float4 dw;
        dw.x = xt0.y - xt0.x; dw.y = xt0.z - xt0.y; dw.z = xt0.w - xt0.z;
        dw.w = (c4 < 63) ? (sxt[rr * 256 + 4 * c4 + 4] - xt0.w) : 0.f;
        float4 v0n, v1n;
        v0n.x = fmaf(sigma, dh.x, u0k[k].x); v0n.y = fmaf(sigma, dh.y, u0k[k].y);
        v0n.z = fmaf(sigma, dh.z, u0k[k].z); v0n.w = fmaf(sigma, dh.w, u0k[k].w);
        v1n.x = fmaf(sigma, dw.x, u1k[k].x); v1n.y = fmaf(sigma, dw.y, u1k[k].y);
        v1n.z = fmaf(sigma, dw.z, u1k[k].z); v1n.w = fmaf(sigma, dw.w, u1k[k].w);
        const int iv4 = bc * 32768 + gh * 64 + c4;
        st4(vnext, iv4, v0n);
        st4(vnext, iv4 + 16384, v1n);
        pa0 += v0n.x*v0n.x + v0n.y*v0n.y + v0n.z*v0n.z + v0n.w*v0n.w;
        pa1 += v1n.x*v1n.x + v1n.y*v1n.y + v1n.z*v1n.z + v1n.w*v1n.w;
    }
    sred[tid] = b ? mk4(0.f, 0.f, pa0, pa1) : mk4(pa0, pa1, 0.f, 0.f);
    __syncthreads();
    for (int s = 128; s > 0; s >>= 1) {
        if (tid < s) {
            float4 a = sred[tid], bb = sred[tid + s];
            a.x += bb.x; a.y += bb.y; a.z += bb.z; a.w += bb.w;
            sred[tid] = a;
        }
        __syncthreads();
    }
    if (tid == 0) st4(pnext, blk, sred[0]);
}

// s=50: final phase B -> x_50, xt_50, u_50 (reads v49 from ws, writes u in d_out: disjoint)
__global__ void __launch_bounds__(256) cp_kC(const float* __restrict__ y,
        const float* __restrict__ lambd, float* __restrict__ x, float* __restrict__ xt,
        float* __restrict__ u, const float* __restrict__ v49,
        const float* __restrict__ pprev, float tau, float chi)
{
    __shared__ float4 sred[256];
    __shared__ float4 s_scale;
    const int tid = threadIdx.x;
    const int blk = blockIdx.x;
    const int bc = blk >> 5;
    const int r0 = (blk & 31) * R;
    const int c4 = tid & 63;
    const int trow = tid >> 6;
    const int b = (bc >= Cc) ? 1 : 0;

    sred[tid] = (tid < NBLK) ? ld4(pprev, tid) : mk4(0, 0, 0, 0);
    __syncthreads();
    for (int s = 128; s > 0; s >>= 1) {
        if (tid < s) {
            float4 a = sred[tid], bb = sred[tid + s];
            a.x += bb.x; a.y += bb.y; a.z += bb.z; a.w += bb.w;
            sred[tid] = a;
        }
        __syncthreads();
    }
    if (tid == 0) {
        const float lamb = expf(lambd[0]);
        float4 S = sred[0];
        s_scale = mk4(lamb / fmaxf(sqrtf(S.x), lamb), lamb / fmaxf(sqrtf(S.y), lamb),
                      lamb / fmaxf(sqrtf(S.z), lamb), lamb / fmaxf(sqrtf(S.w), lamb));
    }
    __syncthreads();
    const float s0 = b ? s_scale.z : s_scale.x;
    const float s1 = b ? s_scale.w : s_scale.y;
    const float inv = 1.0f / (1.0f + tau);
    const float opc = 1.0f + chi;
    #pragma unroll
    for (int k = 0; k < 2; ++k) {
        const int rr = trow + 4 * k;
        const int gh = r0 + rr;
        const int j4 = bc * 16384 + gh * 64 + c4;
        const int iv4 = bc * 32768 + gh * 64 + c4;
        const float4 v0 = ld4(v49, iv4);
        const float4 v1 = ld4(v49, iv4 + 16384);
        float4 u0, u1;
        u0.x = v0.x*s0; u0.y = v0.y*s0; u0.z = v0.z*s0; u0.w = v0.w*s0;
        u1.x = v1.x*s1; u1.y = v1.y*s1; u1.z = v1.z*s1; u1.w = v1.w*s1;
        st4(u, iv4, u0);
        st4(u, iv4 + 16384, u1);
        float nt0 = 0.f, nt1 = 0.f, nt2 = 0.f, nt3 = 0.f;
        if (gh > 0) {
            float4 vm = ld4(v49, iv4 - 64);
            nt0 += vm.x*s0; nt1 += vm.y*s0; nt2 += vm.z*s0; nt3 += vm.w*s0;
        }
        if (gh < Hh - 1) { nt0 -= u0.x; nt1 -= u0.y; nt2 -= u0.z; nt3 -= u0.w; }
        if (c4 > 0) nt0 += v49[((iv4 + 16384) << 2) - 1] * s1;
        nt1 += u1.x; nt2 += u1.y; nt3 += u1.z;
        nt0 -= u1.x; nt1 -= u1.y; nt2 -= u1.z;
        if (c4 < 63) nt3 -= u1.w;
        const float4 xo = ld4(x, j4);
        const float4 yv = ld4(y, j4);
        float4 xp, xtp;
        xp.x = (xo.x + tau * (yv.x - nt0)) * inv;
        xp.y = (xo.y + tau * (yv.y - nt1)) * inv;
        xp.z = (xo.z + tau * (yv.z - nt2)) * inv;
        xp.w = (xo.w + tau * (yv.w - nt3)) * inv;
        xtp.x = opc * xp.x - chi * xo.x;
        xtp.y = opc * xp.y - chi * xo.y;
        xtp.z = opc * xp.z - chi * xo.z;
        xtp.w = opc * xp.w - chi * xo.w;
        st4(x, j4, xp);
        st4(xt, j4, xtp);
    }
}

extern "C" void kernel_launch(void* const* d_in, const int* in_sizes, int n_in,
                              void* d_out, int out_size, void* d_ws, size_t ws_size,
                              hipStream_t stream) {
    (void)in_sizes; (void)n_in; (void)out_size; (void)ws_size;
    const float* y     = (const float*)d_in[0];
    const float* lambd = (const float*)d_in[1];
    float* x  = (float*)d_out;          // [0, NX)
    float* xt = x + NX;                 // [NX, 2NX)
    float* u  = x + 2 * NX;             // [2NX, 2NX+NU)  -- doubles as v ping-pong buf (even steps)
    float* wsv  = (float*)d_ws;         // NU floats       -- v ping-pong buf (odd steps)
    float* pars = wsv + NU;             // 2 * NBLK * 4 floats
    float* xtop = pars + 2 * NBLK * 4;  // 2 * NBLK * 256 floats

    // vbuf(s): where v_s lives
    auto vbuf = [&](int s) -> float* { return (s & 1) ? wsv : u; };
    auto pbuf = [&](int s) -> float* { return pars + (s & 1) * NBLK * 4; };
    auto tbuf = [&](int s) -> float* { return xtop + (s & 1) * NBLK * 256; };

    cp_kA<<<NBLK, 256, 0, stream>>>(y, x, vbuf(0), pbuf(0), tbuf(0));

    float sigma = 0.20412414523193150818f;  // 0.5/sqrt(6)
    float tau   = sigma;
    for (int s = 1; s < KSTEPS; ++s) {
        const float chi = 1.0f / sqrtf(1.0f + tau);      // chi_{s-1}
        const float sigma_s = sigma / chi;               // sigma_s
        cp_kB<<<NBLK, 256, 0, stream>>>(y, lambd, x,
                                        vbuf(s - 1), vbuf(s), pbuf(s - 1), pbuf(s),
                                        tbuf(s - 1), tbuf(s),
                                        sigma_s, tau, chi);
        tau *= chi;
        sigma = sigma_s;
    }
    const float chi49 = 1.0f / sqrtf(1.0f + tau);
    cp_kC<<<NBLK, 256, 0, stream>>>(y, lambd, x, xt, u, vbuf(KSTEPS - 1),
                                    pbuf(KSTEPS - 1), tau, chi49);
}

// Round 4
// 250.266 us; speedup vs baseline: 26.4136x; 1.3137x over previous
//
#include <hip/hip_runtime.h>
#include <math.h>

constexpr int Cc = 3, Hh = 256;
constexpr int NX = 393216;   // 2*3*256*256
constexpr int NU = 786432;
constexpr int R = 4;         // rows per tile
constexpr int NBLK = 384;    // 6 images * 64 tiles
constexpr int KSTEPS = 50;

__device__ __forceinline__ float4 ld4(const float* p, int i) { return ((const float4*)p)[i]; }
__device__ __forceinline__ void st4(float* p, int i, float4 v) { ((float4*)p)[i] = v; }
__device__ __forceinline__ float4 mk4(float a, float b, float c, float d) { return make_float4(a, b, c, d); }

// Barrier-free redundant scale computation: every lane of every wave reads all
// NBLK float4 partials (6 per lane), fixed-order sum + shfl_xor butterfly.
// fp add is commutative -> all lanes get bit-identical sums, deterministic.
__device__ __forceinline__ void scales_head(const float* __restrict__ pprev,
                                            const float* __restrict__ lambd,
                                            int lane, int b, float& s0, float& s1) {
    float4 S = mk4(0.f, 0.f, 0.f, 0.f);
    #pragma unroll
    for (int k = 0; k < 6; ++k) {
        float4 p = ld4(pprev, lane + 64 * k);
        S.x += p.x; S.y += p.y; S.z += p.z; S.w += p.w;
    }
    #pragma unroll
    for (int m = 1; m < 64; m <<= 1) {
        S.x += __shfl_xor(S.x, m, 64);
        S.y += __shfl_xor(S.y, m, 64);
        S.z += __shfl_xor(S.z, m, 64);
        S.w += __shfl_xor(S.w, m, 64);
    }
    const float lamb = expf(lambd[0]);
    const float g0 = lamb / fmaxf(sqrtf(b ? S.z : S.x), lamb);
    const float g1 = lamb / fmaxf(sqrtf(b ? S.w : S.y), lamb);
    s0 = g0; s1 = g1;
}

// s=0: x=y, v0 = nabla(y), partials, xtop = x0 row0 per block
__global__ void __launch_bounds__(256) cp_kA(const float* __restrict__ y,
        float* __restrict__ x, float* __restrict__ vout,
        float* __restrict__ pout, float* __restrict__ xtop)
{
    __shared__ float2 pw[4];
    const int tid = threadIdx.x;
    const int blk = blockIdx.x;
    const int bc = blk >> 6;
    const int r0 = (blk & 63) * R;
    const int c4 = tid & 63;
    const int trow = tid >> 6;
    const int b = (bc >= Cc) ? 1 : 0;
    const int gh = r0 + trow;
    const int j4 = bc * 16384 + gh * 64 + c4;
    const float4 yv = ld4(y, j4);
    st4(x, j4, yv);
    if (trow == 0) st4(xtop, blk * 64 + c4, yv);
    float4 dh = mk4(0.f, 0.f, 0.f, 0.f);
    if (gh < Hh - 1) {
        float4 yn = ld4(y, j4 + 64);
        dh.x = yn.x - yv.x; dh.y = yn.y - yv.y; dh.z = yn.z - yv.z; dh.w = yn.w - yv.w;
    }
    float4 dw;
    dw.x = yv.y - yv.x; dw.y = yv.z - yv.y; dw.z = yv.w - yv.z;
    float ynx = __shfl_down(yv.x, 1, 64);
    dw.w = (c4 < 63) ? (ynx - yv.w) : 0.f;
    const int iv4 = bc * 32768 + gh * 64 + c4;
    st4(vout, iv4, dh);
    st4(vout, iv4 + 16384, dw);
    float pa0 = dh.x*dh.x + dh.y*dh.y + dh.z*dh.z + dh.w*dh.w;
    float pa1 = dw.x*dw.x + dw.y*dw.y + dw.z*dw.z + dw.w*dw.w;
    #pragma unroll
    for (int m = 1; m < 64; m <<= 1) {
        pa0 += __shfl_xor(pa0, m, 64);
        pa1 += __shfl_xor(pa1, m, 64);
    }
    if (c4 == 0) pw[trow] = make_float2(pa0, pa1);
    __syncthreads();
    if (tid == 0) {
        float q0 = pw[0].x + pw[1].x + pw[2].x + pw[3].x;
        float q1 = pw[0].y + pw[1].y + pw[2].y + pw[3].y;
        st4(pout, blk, b ? mk4(0.f, 0.f, q0, q1) : mk4(q0, q1, 0.f, 0.f));
    }
}

// fused: scales(s-1) -> phaseB(s-1) -> phaseA(s)
__global__ void __launch_bounds__(256) cp_kB(const float* __restrict__ y,
        const float* __restrict__ lambd, float* __restrict__ x,
        const float* __restrict__ vprev, float* __restrict__ vnext,
        const float* __restrict__ pprev, float* __restrict__ pnext,
        const float* __restrict__ xtop_prev, float* __restrict__ xtop_next,
        float sigma, float tau, float chi)
{
    __shared__ float sxt[5 * 256];
    __shared__ float2 pw[4];
    const int tid = threadIdx.x;
    const int blk = blockIdx.x;
    const int bc = blk >> 6;
    const int tile = blk & 63;
    const int r0 = tile * R;
    const int c4 = tid & 63;
    const int trow = tid >> 6;
    const int b = (bc >= Cc) ? 1 : 0;

    float s0, s1;
    scales_head(pprev, lambd, c4, b, s0, s1);

    const float inv = 1.0f / (1.0f + tau);
    const float opc = 1.0f + chi;
    const int gh = r0 + trow;
    const int j4 = bc * 16384 + gh * 64 + c4;
    const int iv4 = bc * 32768 + gh * 64 + c4;

    // ---- phase B, own row ----
    float4 u0, u1, xtp;
    {
        const float4 v0 = ld4(vprev, iv4);
        const float4 v1 = ld4(vprev, iv4 + 16384);
        u0.x = v0.x*s0; u0.y = v0.y*s0; u0.z = v0.z*s0; u0.w = v0.w*s0;
        u1.x = v1.x*s1; u1.y = v1.y*s1; u1.z = v1.z*s1; u1.w = v1.w*s1;
        float nt0 = 0.f, nt1 = 0.f, nt2 = 0.f, nt3 = 0.f;
        if (gh > 0) {
            float4 vm = ld4(vprev, iv4 - 64);
            nt0 += vm.x*s0; nt1 += vm.y*s0; nt2 += vm.z*s0; nt3 += vm.w*s0;
        }
        if (gh < Hh - 1) { nt0 -= u0.x; nt1 -= u0.y; nt2 -= u0.z; nt3 -= u0.w; }
        float ul = __shfl_up(u1.w, 1, 64);
        if (c4 > 0) nt0 += ul;
        nt1 += u1.x; nt2 += u1.y; nt3 += u1.z;
        nt0 -= u1.x; nt1 -= u1.y; nt2 -= u1.z;
        if (c4 < 63) nt3 -= u1.w;
        const float4 xo = ld4(x, j4);
        const float4 yv = ld4(y, j4);
        float4 xp;
        xp.x = (xo.x + tau * (yv.x - nt0)) * inv;
        xp.y = (xo.y + tau * (yv.y - nt1)) * inv;
        xp.z = (xo.z + tau * (yv.z - nt2)) * inv;
        xp.w = (xo.w + tau * (yv.w - nt3)) * inv;
        xtp.x = opc * xp.x - chi * xo.x;
        xtp.y = opc * xp.y - chi * xo.y;
        xtp.z = opc * xp.z - chi * xo.z;
        xtp.w = opc * xp.w - chi * xo.w;
        if (trow > 0) ((float4*)(sxt + trow * 256))[c4] = xtp;
        st4(x, j4, xp);
        if (trow == 0) st4(xtop_next, blk * 64 + c4, xp);
    }
    // ---- phase B, redundant halo row r0+4 (wave 0) ----
    if (trow == 0 && tile < 63) {
        const int gh2 = r0 + 4;                 // in [4,252] -> interior in h
        const int j4h = bc * 16384 + gh2 * 64 + c4;
        const int iv4h = bc * 32768 + gh2 * 64 + c4;
        const float4 v0 = ld4(vprev, iv4h);
        const float4 v1 = ld4(vprev, iv4h + 16384);
        float4 h0, h1;
        h0.x = v0.x*s0; h0.y = v0.y*s0; h0.z = v0.z*s0; h0.w = v0.w*s0;
        h1.x = v1.x*s1; h1.y = v1.y*s1; h1.z = v1.z*s1; h1.w = v1.w*s1;
        float4 vm = ld4(vprev, iv4h - 64);
        float nt0 = vm.x*s0 - h0.x, nt1 = vm.y*s0 - h0.y,
              nt2 = vm.z*s0 - h0.z, nt3 = vm.w*s0 - h0.w;
        float ul = __shfl_up(h1.w, 1, 64);
        if (c4 > 0) nt0 += ul;
        nt1 += h1.x; nt2 += h1.y; nt3 += h1.z;
        nt0 -= h1.x; nt1 -= h1.y; nt2 -= h1.z;
        if (c4 < 63) nt3 -= h1.w;
        const float4 xo = ld4(xtop_prev, (blk + 1) * 64 + c4);
        const float4 yv = ld4(y, j4h);
        float4 xp, xth;
        xp.x = (xo.x + tau * (yv.x - nt0)) * inv;
        xp.y = (xo.y + tau * (yv.y - nt1)) * inv;
        xp.z = (xo.z + tau * (yv.z - nt2)) * inv;
        xp.w = (xo.w + tau * (yv.w - nt3)) * inv;
        xth.x = opc * xp.x - chi * xo.x;
        xth.y = opc * xp.y - chi * xo.y;
        xth.z = opc * xp.z - chi * xo.z;
        xth.w = opc * xp.w - chi * xo.w;
        ((float4*)(sxt + 4 * 256))[c4] = xth;
    }
    __syncthreads();

    // ---- phase A (step s) ----
    float4 dh = mk4(0.f, 0.f, 0.f, 0.f);
    if (gh < Hh - 1) {
        float4 xn = ((const float4*)(sxt + (trow + 1) * 256))[c4];
        dh.x = xn.x - xtp.x; dh.y = xn.y - xtp.y; dh.z = xn.z - xtp.z; dh.w = xn.w - xtp.w;
    }
    float4 dw;
    dw.x = xtp.y - xtp.x; dw.y = xtp.z - xtp.y; dw.z = xtp.w - xtp.z;
    float xnx = __shfl_down(xtp.x, 1, 64);
    dw.w = (c4 < 63) ? (xnx - xtp.w) : 0.f;
    float4 v0n, v1n;
    v0n.x = fmaf(sigma, dh.x, u0.x); v0n.y = fmaf(sigma, dh.y, u0.y);
    v0n.z = fmaf(sigma, dh.z, u0.z); v0n.w = fmaf(sigma, dh.w, u0.w);
    v1n.x = fmaf(sigma, dw.x, u1.x); v1n.y = fmaf(sigma, dw.y, u1.y);
    v1n.z = fmaf(sigma, dw.z, u1.z); v1n.w = fmaf(sigma, dw.w, u1.w);
    st4(vnext, iv4, v0n);
    st4(vnext, iv4 + 16384, v1n);
    float pa0 = v0n.x*v0n.x + v0n.y*v0n.y + v0n.z*v0n.z + v0n.w*v0n.w;
    float pa1 = v1n.x*v1n.x + v1n.y*v1n.y + v1n.z*v1n.z + v1n.w*v1n.w;
    #pragma unroll
    for (int m = 1; m < 64; m <<= 1) {
        pa0 += __shfl_xor(pa0, m, 64);
        pa1 += __shfl_xor(pa1, m, 64);
    }
    if (c4 == 0) pw[trow] = make_float2(pa0, pa1);
    __syncthreads();
    if (tid == 0) {
        float q0 = pw[0].x + pw[1].x + pw[2].x + pw[3].x;
        float q1 = pw[0].y + pw[1].y + pw[2].y + pw[3].y;
        st4(pnext, blk, b ? mk4(0.f, 0.f, q0, q1) : mk4(q0, q1, 0.f, 0.f));
    }
}

// s=50: final phase B -> x_50, xt_50, u_50. No barriers.
__global__ void __launch_bounds__(256) cp_kC(const float* __restrict__ y,
        const float* __restrict__ lambd, float* __restrict__ x, float* __restrict__ xt,
        float* __restrict__ u, const float* __restrict__ v49,
        const float* __restrict__ pprev, float tau, float chi)
{
    const int tid = threadIdx.x;
    const int blk = blockIdx.x;
    const int bc = blk >> 6;
    const int r0 = (blk & 63) * R;
    const int c4 = tid & 63;
    const int trow = tid >> 6;
    const int b = (bc >= Cc) ? 1 : 0;

    float s0, s1;
    scales_head(pprev, lambd, c4, b, s0, s1);

    const float inv = 1.0f / (1.0f + tau);
    const float opc = 1.0f + chi;
    const int gh = r0 + trow;
    const int j4 = bc * 16384 + gh * 64 + c4;
    const int iv4 = bc * 32768 + gh * 64 + c4;
    const float4 v0 = ld4(v49, iv4);
    const float4 v1 = ld4(v49, iv4 + 16384);
    float4 u0, u1;
    u0.x = v0.x*s0; u0.y = v0.y*s0; u0.z = v0.z*s0; u0.w = v0.w*s0;
    u1.x = v1.x*s1; u1.y = v1.y*s1; u1.z = v1.z*s1; u1.w = v1.w*s1;
    st4(u, iv4, u0);
    st4(u, iv4 + 16384, u1);
    float nt0 = 0.f, nt1 = 0.f, nt2 = 0.f, nt3 = 0.f;
    if (gh > 0) {
        float4 vm = ld4(v49, iv4 - 64);
        nt0 += vm.x*s0; nt1 += vm.y*s0; nt2 += vm.z*s0; nt3 += vm.w*s0;
    }
    if (gh < Hh - 1) { nt0 -= u0.x; nt1 -= u0.y; nt2 -= u0.z; nt3 -= u0.w; }
    float ul = __shfl_up(u1.w, 1, 64);
    if (c4 > 0) nt0 += ul;
    nt1 += u1.x; nt2 += u1.y; nt3 += u1.z;
    nt0 -= u1.x; nt1 -= u1.y; nt2 -= u1.z;
    if (c4 < 63) nt3 -= u1.w;
    const float4 xo = ld4(x, j4);
    const float4 yv = ld4(y, j4);
    float4 xp, xtp;
    xp.x = (xo.x + tau * (yv.x - nt0)) * inv;
    xp.y = (xo.y + tau * (yv.y - nt1)) * inv;
    xp.z = (xo.z + tau * (yv.z - nt2)) * inv;
    xp.w = (xo.w + tau * (yv.w - nt3)) * inv;
    xtp.x = opc * xp.x - chi * xo.x;
    xtp.y = opc * xp.y - chi * xo.y;
    xtp.z = opc * xp.z - chi * xo.z;
    xtp.w = opc * xp.w - chi * xo.w;
    st4(x, j4, xp);
    st4(xt, j4, xtp);
}

extern "C" void kernel_launch(void* const* d_in, const int* in_sizes, int n_in,
                              void* d_out, int out_size, void* d_ws, size_t ws_size,
                              hipStream_t stream) {
    (void)in_sizes; (void)n_in; (void)out_size; (void)ws_size;
    const float* y     = (const float*)d_in[0];
    const float* lambd = (const float*)d_in[1];
    float* x  = (float*)d_out;          // [0, NX)
    float* xt = x + NX;                 // [NX, 2NX)
    float* u  = x + 2 * NX;             // [2NX, 2NX+NU) -- doubles as v buf (even steps)
    float* wsv  = (float*)d_ws;         // NU floats      -- v buf (odd steps)
    float* pars = wsv + NU;             // 2 * NBLK * 4 floats
    float* xtop = pars + 2 * NBLK * 4;  // 2 * NBLK * 256 floats

    auto vbuf = [&](int s) -> float* { return (s & 1) ? wsv : u; };
    auto pbuf = [&](int s) -> float* { return pars + (s & 1) * NBLK * 4; };
    auto tbuf = [&](int s) -> float* { return xtop + (s & 1) * NBLK * 256; };

    cp_kA<<<NBLK, 256, 0, stream>>>(y, x, vbuf(0), pbuf(0), tbuf(0));

    float sigma = 0.20412414523193150818f;  // 0.5/sqrt(6)
    float tau   = sigma;
    for (int s = 1; s < KSTEPS; ++s) {
        const float chi = 1.0f / sqrtf(1.0f + tau);      // chi_{s-1}
        const float sigma_s = sigma / chi;               // sigma_s
        cp_kB<<<NBLK, 256, 0, stream>>>(y, lambd, x,
                                        vbuf(s - 1), vbuf(s), pbuf(s - 1), pbuf(s),
                                        tbuf(s - 1), tbuf(s),
                                        sigma_s, tau, chi);
        tau *= chi;
        sigma = sigma_s;
    }
    const float chi49 = 1.0f / sqrtf(1.0f + tau);
    cp_kC<<<NBLK, 256, 0, stream>>>(y, lambd, x, xt, u, vbuf(KSTEPS - 1),
                                    pbuf(KSTEPS - 1), tau, chi49);
}